// Round 1
// baseline (367.046 us; speedup 1.0000x reference)
//
#include <hip/hip_runtime.h>

#define BATCH 4096
#define NNEG  200
#define DIM   64
#define NPART 4
#define NCENT 256
#define CDIM  16
#define CPAD  17   // 16 values + 1 slot for the row norm; odd stride kills LDS bank conflicts

// Kernel 1: vector-quantize each user embedding.
// grid = (BATCH/4, NPART), block = 256 (4 waves). Wave w handles user b = bx*4+w,
// partition p = blockIdx.y. Each lane scores 4 centroids (k = j*64 + lane),
// then a 64-lane butterfly argmax picks the winner (first-index tie-break,
// matching jnp.argmax).
__global__ __launch_bounds__(256) void qvae_encode_kernel(
    const int*   __restrict__ user_id,
    const float* __restrict__ user_table,
    const float* __restrict__ centroids,   // [NPART][NCENT][CDIM]
    const float* __restrict__ gumbel_u,    // [NPART][BATCH][NCENT]
    float*       __restrict__ user_vec)    // [BATCH][DIM]
{
    __shared__ float cent[NCENT * CPAD];

    const int p    = blockIdx.y;
    const int tid  = threadIdx.x;
    const int w    = tid >> 6;
    const int lane = tid & 63;
    const int b    = blockIdx.x * 4 + w;

    // Stage this partition's centroids into LDS (coalesced global reads).
    const float* cp = centroids + (size_t)p * NCENT * CDIM;
    for (int idx = tid; idx < NCENT * CDIM; idx += 256) {
        int row = idx >> 4, col = idx & 15;
        cent[row * CPAD + col] = cp[idx];
    }
    __syncthreads();
    // Each thread computes one row norm into the pad slot.
    {
        float s = 0.f;
        #pragma unroll
        for (int c = 0; c < CDIM; ++c) { float v = cent[tid * CPAD + c]; s += v * v; }
        cent[tid * CPAD + CDIM] = s;
    }
    __syncthreads();

    // Load this (b,p)'s 16-float user sub-embedding (wave-uniform row; L1 broadcast).
    const int uid = user_id[b];
    const float* up = user_table + (size_t)uid * DIM + p * CDIM;
    float ue[CDIM];
    #pragma unroll
    for (int i = 0; i < 4; ++i) {
        float4 v = ((const float4*)up)[i];
        ue[4*i+0] = v.x; ue[4*i+1] = v.y; ue[4*i+2] = v.z; ue[4*i+3] = v.w;
    }
    float ue2 = 0.f;
    #pragma unroll
    for (int c = 0; c < CDIM; ++c) ue2 += ue[c] * ue[c];

    // Score 4 centroids per lane; gumbel loads are coalesced across lanes.
    const float* gp = gumbel_u + ((size_t)p * BATCH + b) * NCENT;
    float best_s = -INFINITY;
    int   best_k = 0;
    #pragma unroll
    for (int j = 0; j < 4; ++j) {
        const int k = j * 64 + lane;
        float u = gp[k];
        float g = -logf(-logf(u));           // gumbel noise
        float dot = 0.f, c2 = cent[k * CPAD + CDIM];
        #pragma unroll
        for (int c = 0; c < CDIM; ++c) dot += ue[c] * cent[k * CPAD + c];
        float dist = (ue2 + c2) - 2.0f * dot;
        float s = -dist + g;
        if (s > best_s) { best_s = s; best_k = k; }   // strict > keeps smallest k
    }

    // 64-lane butterfly argmax; tie -> smaller k (matches jnp.argmax first-index).
    #pragma unroll
    for (int m = 1; m < 64; m <<= 1) {
        float so = __shfl_xor(best_s, m, 64);
        int   ko = __shfl_xor(best_k, m, 64);
        if (so > best_s || (so == best_s && ko < best_k)) { best_s = so; best_k = ko; }
    }

    // Winning centroid row becomes the quantized user sub-vector.
    if (lane < CDIM) {
        user_vec[(size_t)b * DIM + p * CDIM + lane] = cent[best_k * CPAD + lane];
    }
}

// Kernel 2: pos/neg scores. One block per user b; thread j in [0,200] handles
// item j (j==0 -> pos, else neg j-1). User vector staged in LDS (broadcast
// reads), item rows are 256B-aligned float4 gathers (table is 25.6 MB ->
// mostly L2/L3 hits).
__global__ __launch_bounds__(256) void qvae_score_kernel(
    const int*   __restrict__ pos_id,
    const int*   __restrict__ neg_ids,
    const float* __restrict__ item_table,
    const float* __restrict__ user_vec,
    float*       __restrict__ out)   // [BATCH] pos then [BATCH][NNEG] neg
{
    __shared__ float uv[DIM];
    const int b   = blockIdx.x;
    const int tid = threadIdx.x;
    if (tid < DIM) uv[tid] = user_vec[(size_t)b * DIM + tid];
    __syncthreads();
    if (tid > NNEG) return;

    const int id = (tid == 0) ? pos_id[b] : neg_ids[(size_t)b * NNEG + tid - 1];
    const float4* ip = (const float4*)(item_table + (size_t)id * DIM);
    const float4* u4 = (const float4*)uv;
    float s = 0.f;
    #pragma unroll
    for (int i = 0; i < DIM / 4; ++i) {
        float4 it = ip[i];
        float4 uu = u4[i];
        s += it.x * uu.x + it.y * uu.y + it.z * uu.z + it.w * uu.w;
    }
    if (tid == 0) out[b] = s;
    else          out[BATCH + (size_t)b * NNEG + (tid - 1)] = s;
}

extern "C" void kernel_launch(void* const* d_in, const int* in_sizes, int n_in,
                              void* d_out, int out_size, void* d_ws, size_t ws_size,
                              hipStream_t stream) {
    const int*   user_id    = (const int*)  d_in[0];
    const int*   pos_id     = (const int*)  d_in[1];
    const int*   neg_ids    = (const int*)  d_in[2];
    const float* user_table = (const float*)d_in[3];
    const float* centroids  = (const float*)d_in[4];
    const float* item_table = (const float*)d_in[5];
    const float* gumbel_u   = (const float*)d_in[6];
    float* out = (float*)d_out;
    float* uv  = (float*)d_ws;   // BATCH*DIM floats = 1 MB scratch

    qvae_encode_kernel<<<dim3(BATCH / 4, NPART), 256, 0, stream>>>(
        user_id, user_table, centroids, gumbel_u, uv);
    qvae_score_kernel<<<BATCH, 256, 0, stream>>>(
        pos_id, neg_ids, item_table, uv, out);
}

// Round 2
// 357.004 us; speedup vs baseline: 1.0281x; 1.0281x over previous
//
#include <hip/hip_runtime.h>

#define BATCH 4096
#define NNEG  200
#define NITEM 201   // pos + 200 neg
#define DIM   64
#define NPART 4
#define NCENT 256
#define CDIM  16
#define CPAD  17   // 16 values + 1 slot for the row norm; odd stride kills LDS bank conflicts

// Kernel 1: vector-quantize each user embedding.
// grid = (BATCH/4, NPART), block = 256 (4 waves). Wave w handles user b = bx*4+w,
// partition p = blockIdx.y. Each lane scores 4 centroids (k = j*64 + lane),
// then a 64-lane butterfly argmax picks the winner (first-index tie-break,
// matching jnp.argmax).
__global__ __launch_bounds__(256) void qvae_encode_kernel(
    const int*   __restrict__ user_id,
    const float* __restrict__ user_table,
    const float* __restrict__ centroids,   // [NPART][NCENT][CDIM]
    const float* __restrict__ gumbel_u,    // [NPART][BATCH][NCENT]
    float*       __restrict__ user_vec)    // [BATCH][DIM]
{
    __shared__ float cent[NCENT * CPAD];

    const int p    = blockIdx.y;
    const int tid  = threadIdx.x;
    const int w    = tid >> 6;
    const int lane = tid & 63;
    const int b    = blockIdx.x * 4 + w;

    // Stage this partition's centroids into LDS (coalesced global reads).
    const float* cp = centroids + (size_t)p * NCENT * CDIM;
    for (int idx = tid; idx < NCENT * CDIM; idx += 256) {
        int row = idx >> 4, col = idx & 15;
        cent[row * CPAD + col] = cp[idx];
    }
    __syncthreads();
    // Each thread computes one row norm into the pad slot.
    {
        float s = 0.f;
        #pragma unroll
        for (int c = 0; c < CDIM; ++c) { float v = cent[tid * CPAD + c]; s += v * v; }
        cent[tid * CPAD + CDIM] = s;
    }
    __syncthreads();

    // Load this (b,p)'s 16-float user sub-embedding (wave-uniform row; L1 broadcast).
    const int uid = user_id[b];
    const float* up = user_table + (size_t)uid * DIM + p * CDIM;
    float ue[CDIM];
    #pragma unroll
    for (int i = 0; i < 4; ++i) {
        float4 v = ((const float4*)up)[i];
        ue[4*i+0] = v.x; ue[4*i+1] = v.y; ue[4*i+2] = v.z; ue[4*i+3] = v.w;
    }
    float ue2 = 0.f;
    #pragma unroll
    for (int c = 0; c < CDIM; ++c) ue2 += ue[c] * ue[c];

    // Score 4 centroids per lane; gumbel loads are coalesced across lanes.
    const float* gp = gumbel_u + ((size_t)p * BATCH + b) * NCENT;
    float best_s = -INFINITY;
    int   best_k = 0;
    #pragma unroll
    for (int j = 0; j < 4; ++j) {
        const int k = j * 64 + lane;
        float u = gp[k];
        float g = -logf(-logf(u));           // gumbel noise
        float dot = 0.f, c2 = cent[k * CPAD + CDIM];
        #pragma unroll
        for (int c = 0; c < CDIM; ++c) dot += ue[c] * cent[k * CPAD + c];
        float dist = (ue2 + c2) - 2.0f * dot;
        float s = -dist + g;
        if (s > best_s) { best_s = s; best_k = k; }   // strict > keeps smallest k
    }

    // 64-lane butterfly argmax; tie -> smaller k (matches jnp.argmax first-index).
    #pragma unroll
    for (int m = 1; m < 64; m <<= 1) {
        float so = __shfl_xor(best_s, m, 64);
        int   ko = __shfl_xor(best_k, m, 64);
        if (so > best_s || (so == best_s && ko < best_k)) { best_s = so; best_k = ko; }
    }

    // Winning centroid row becomes the quantized user sub-vector.
    if (lane < CDIM) {
        user_vec[(size_t)b * DIM + p * CDIM + lane] = cent[best_k * CPAD + lane];
    }
}

// Kernel 2: pos/neg scores, coalesced gather.
// One block per user b. 16 lanes cooperate on one item row: lane (tid&15)
// loads float4 #(tid&15) of the 256B row -> one load instruction covers four
// full rows, perfectly line-aligned. 4-step shfl_xor reduces within the
// 16-lane cluster. Ids staged in LDS (coalesced), results staged in LDS for a
// fully coalesced final store.
__global__ __launch_bounds__(256) void qvae_score_kernel(
    const int*   __restrict__ pos_id,
    const int*   __restrict__ neg_ids,
    const float* __restrict__ item_table,
    const float* __restrict__ user_vec,
    float*       __restrict__ out)   // [BATCH] pos then [BATCH][NNEG] neg
{
    __shared__ float4 uv4[DIM / 4];
    __shared__ int    ids[NITEM];
    __shared__ float  res[NITEM];

    const int b   = blockIdx.x;
    const int tid = threadIdx.x;

    if (tid < DIM / 4) uv4[tid] = ((const float4*)(user_vec + (size_t)b * DIM))[tid];
    if (tid == 0)           ids[0]   = pos_id[b];
    else if (tid <= NNEG)   ids[tid] = neg_ids[(size_t)b * NNEG + tid - 1];
    __syncthreads();

    const int grp = tid >> 4;   // 16 clusters of 16 lanes
    const int l16 = tid & 15;
    const float4 u = uv4[l16];  // one-time LDS read, 2-way aliasing (free)

    for (int item = grp; item < NITEM; item += 16) {
        const float4 v = ((const float4*)(item_table + (size_t)ids[item] * DIM))[l16];
        float s = v.x * u.x + v.y * u.y + v.z * u.z + v.w * u.w;
        s += __shfl_xor(s, 1, 64);
        s += __shfl_xor(s, 2, 64);
        s += __shfl_xor(s, 4, 64);
        s += __shfl_xor(s, 8, 64);
        if (l16 == 0) res[item] = s;
    }
    __syncthreads();

    if (tid == 0)   out[b] = res[0];
    if (tid < NNEG) out[BATCH + (size_t)b * NNEG + tid] = res[tid + 1];
}

extern "C" void kernel_launch(void* const* d_in, const int* in_sizes, int n_in,
                              void* d_out, int out_size, void* d_ws, size_t ws_size,
                              hipStream_t stream) {
    const int*   user_id    = (const int*)  d_in[0];
    const int*   pos_id     = (const int*)  d_in[1];
    const int*   neg_ids    = (const int*)  d_in[2];
    const float* user_table = (const float*)d_in[3];
    const float* centroids  = (const float*)d_in[4];
    const float* item_table = (const float*)d_in[5];
    const float* gumbel_u   = (const float*)d_in[6];
    float* out = (float*)d_out;
    float* uv  = (float*)d_ws;   // BATCH*DIM floats = 1 MB scratch

    qvae_encode_kernel<<<dim3(BATCH / 4, NPART), 256, 0, stream>>>(
        user_id, user_table, centroids, gumbel_u, uv);
    qvae_score_kernel<<<BATCH, 256, 0, stream>>>(
        pos_id, neg_ids, item_table, uv, out);
}